// Round 14
// baseline (213.175 us; speedup 1.0000x reference)
//
#include <hip/hip_runtime.h>
#include <hip/hip_fp16.h>

#define NN 50000        // nodes
#define NE 800000       // edges (without self loops; 800000 = 128*6250)
#define ET 850000       // edges + self loops
#define GD 128          // input feature dim
#define D1 128          // HEADS*H1
#define NH 4            // heads layer 1
#define D2 64           // layer-2 dim
#define NB_SCAN 196     // ceil(NN/256)
#define NBP 1024        // bn partial blocks
#define NXCD 8
#define NPX 6250        // nodes per shard (= per XCD for gat swizzle)
#define HSL 128         // hist slices
#define ESL 6250        // edges per slice = NE/HSL (exact)
#define NHB 1024        // hist blocks = NXCD * HSL
#define CAP 1024        // compact-list capacity per block (mean 781, ~9 sigma margin)
#define NGB (NXCD * 1563)  // gat blocks: 4 nodes/block, 1563 groups per shard

typedef unsigned short u16;
typedef _Float16 half8_t __attribute__((ext_vector_type(8)));
typedef float    f32x4_t __attribute__((ext_vector_type(4)));

__device__ __forceinline__ float lrelu(float x, float s) { return x > 0.f ? x : s * x; }

// ---------------- init: permute/cvt weights ----------------
__global__ void k_prepw(const float* __restrict__ W1, const float* __restrict__ W2,
                        __half* __restrict__ Wp1, __half* __restrict__ Wp2) {
    int idx = blockIdx.x * 256 + threadIdx.x;
    if (idx < 16384) {
        int i = idx & 7, l = (idx >> 3) & 63, nt = (idx >> 9) & 7, kk = idx >> 12;
        int k = kk * 32 + (l >> 4) * 8 + i, n = nt * 16 + (l & 15);
        Wp1[idx] = __float2half(W1[k * D1 + n]);
    } else if (idx < 24576) {
        int x2 = idx - 16384;
        int i = x2 & 7, l = (x2 >> 3) & 63, nt = (x2 >> 9) & 3, kk = x2 >> 11;
        int k = kk * 32 + (l >> 4) * 8 + i, n = nt * 16 + (l & 15);
        Wp2[x2] = __float2half(W2[k * D2 + n]);
    }
}

// ---------------- fused: LDS u16-hist CSR build (blocks [0,NHB)) + MFMA GEMM1 ----------------
__global__ void k_histgemm1(const int* __restrict__ ei,
                            unsigned* __restrict__ ulist, u16* __restrict__ plist,
                            u16* __restrict__ partial, int* __restrict__ mcount,
                            const float* __restrict__ x, const half8_t* __restrict__ wp,
                            const float* __restrict__ as, const float* __restrict__ ad,
                            __half* __restrict__ xw, float* __restrict__ al_s,
                            float* __restrict__ al_d) {
    __shared__ unsigned lh[NPX / 2];   // 3125 u32 = 6250 u16 counters
    __shared__ unsigned lk;
    if (blockIdx.x < NHB) {
        const int s = blockIdx.x & (NXCD - 1), j = blockIdx.x >> 3;
        const int lo = s * NPX;
        for (int i = threadIdx.x; i < NPX / 2; i += 256) lh[i] = 0u;
        if (threadIdx.x == 0) lk = 0u;
        __syncthreads();
        const int e0 = j * ESL;
        const size_t ub = (size_t)blockIdx.x * CAP;
        for (int e = e0 + threadIdx.x; e < e0 + ESL; e += 256) {
            int d = ei[NE + e];
            unsigned dl = (unsigned)(d - lo);
            if (dl < (unsigned)NPX) {
                unsigned old = atomicAdd(&lh[dl >> 1], (dl & 1) ? 0x10000u : 1u);
                unsigned p = (old >> ((dl & 1) * 16)) & 0xffffu;
                unsigned k = atomicAdd(&lk, 1u);
                if (k < CAP) {
                    ulist[ub + k] = (dl << 16) | (unsigned)ei[e];
                    plist[ub + k] = (u16)p;
                }
            }
        }
        __syncthreads();
        unsigned* pout = (unsigned*)(partial + (size_t)blockIdx.x * NPX);
        for (int i = threadIdx.x; i < NPX / 2; i += 256) pout[i] = lh[i];
        if (threadIdx.x == 0) mcount[blockIdx.x] = (int)lk;
        return;
    }
    const int strip = (blockIdx.x - NHB) * 4 + (threadIdx.x >> 6);
    if (strip >= NN / 16) return;
    const int l = threadIdx.x & 63;
    const int row0 = strip * 16;
    const int c = l & 15, g = l >> 4;
    const float* xrow = x + (size_t)(row0 + c) * GD;

    f32x4_t acc[8];
#pragma unroll
    for (int nt = 0; nt < 8; nt++) acc[nt] = (f32x4_t){0.f, 0.f, 0.f, 0.f};

#pragma unroll
    for (int kk = 0; kk < 4; kk++) {
        const int koff = kk * 32 + g * 8;
        f32x4_t a0 = *(const f32x4_t*)(xrow + koff);
        f32x4_t a1 = *(const f32x4_t*)(xrow + koff + 4);
        half8_t af;
#pragma unroll
        for (int i = 0; i < 4; i++) { af[i] = (_Float16)a0[i]; af[i + 4] = (_Float16)a1[i]; }
#pragma unroll
        for (int nt = 0; nt < 8; nt++) {
            half8_t bf = wp[(kk * 8 + nt) * 64 + l];
            acc[nt] = __builtin_amdgcn_mfma_f32_16x16x32_f16(af, bf, acc[nt], 0, 0, 0);
        }
    }

    float asv[8], adv[8];
#pragma unroll
    for (int nt = 0; nt < 8; nt++) { asv[nt] = as[nt * 16 + c]; adv[nt] = ad[nt * 16 + c]; }

#pragma unroll
    for (int r = 0; r < 4; r++) {
        const int row = row0 + g * 4 + r;
        __half* xwr = xw + (size_t)row * D1;
        float hs[4] = {0.f, 0.f, 0.f, 0.f}, hd[4] = {0.f, 0.f, 0.f, 0.f};
#pragma unroll
        for (int nt = 0; nt < 8; nt++) {
            float v = acc[nt][r];
            xwr[nt * 16 + c] = __float2half(v);
            hs[nt >> 1] += v * asv[nt];
            hd[nt >> 1] += v * adv[nt];
        }
#pragma unroll
        for (int m = 1; m <= 8; m <<= 1) {
#pragma unroll
            for (int h = 0; h < 4; h++) { hs[h] += __shfl_xor(hs[h], m); hd[h] += __shfl_xor(hd[h], m); }
        }
        if (c == 0) {
#pragma unroll
            for (int h = 0; h < 4; h++) { al_s[row * NH + h] = hs[h]; al_d[row * NH + h] = hd[h]; }
        }
    }
}

// ---------------- merged: per-node slice-prefix (in place) + cnt + block sums ----------------
__global__ void k_prefsum(u16* __restrict__ partial, int* __restrict__ cnt,
                          int* __restrict__ part) {
    __shared__ int r[256];
    int t = threadIdx.x, d = blockIdx.x * 256 + t;
    int run = 0;
    if (d < NN) {
        int s = d / NPX, dl = d - s * NPX;
        for (int j = 0; j < HSL; j++) {
            size_t idx = (size_t)(j * NXCD + s) * NPX + dl;   // block b = j*8+s
            int v = partial[idx];
            partial[idx] = (u16)run;
            run += v;
        }
        run += 1;             // +1: self-loop occupies slot 0 of each row
        cnt[d] = run;
    }
    r[t] = (d < NN) ? run : 0;
    __syncthreads();
    for (int s2 = 128; s2 >= 1; s2 >>= 1) {
        if (t < s2) r[t] += r[t + s2];
        __syncthreads();
    }
    if (t == 0) part[blockIdx.x] = r[0];
}

__global__ void k_scanfix(const int* __restrict__ cnt, const int* __restrict__ part,
                          int* __restrict__ row_ptr) {
    __shared__ int pp[256];
    __shared__ int r[256];
    int b = blockIdx.x, t = threadIdx.x, i = b * 256 + t;
    pp[t] = (t < NB_SCAN) ? part[t] : 0;
    int v = (i < NN) ? cnt[i] : 0;
    r[t] = v;
    __syncthreads();
    for (int off = 1; off < 256; off <<= 1) {
        int pv = (t >= off) ? pp[t - off] : 0;
        int rv = (t >= off) ? r[t - off] : 0;
        __syncthreads();
        pp[t] += pv; r[t] += rv;
        __syncthreads();
    }
    int pbase = b ? pp[b - 1] : 0;
    if (i < NN) row_ptr[i] = pbase + (t ? r[t - 1] : 0);
    if (i == NN - 1) row_ptr[NN] = pbase + r[t];
}

// ---------------- CSR fill from compact lists + self-loops (no atomics) ----------------
__global__ void k_fill_x(const int* __restrict__ row_ptr, const u16* __restrict__ P,
                         const unsigned* __restrict__ ulist, const u16* __restrict__ plist,
                         const int* __restrict__ mcount, u16* __restrict__ csr_src) {
    const int b = blockIdx.x;
    if (b < NHB) {
        const int s = b & (NXCD - 1);
        const int lo = s * NPX;
        const int m = min(mcount[b], CAP);
        const size_t ub = (size_t)b * CAP;
        const u16* Pb = P + (size_t)b * NPX;
        for (int k = threadIdx.x; k < m; k += 256) {
            unsigned u = ulist[ub + k];
            int dl = (int)(u >> 16);
            int base = row_ptr[lo + dl] + 1 + (int)Pb[dl] + (int)plist[ub + k];
            csr_src[base] = (u16)(u & 0xffffu);
        }
        return;
    }
    const int b2 = b - NHB;                 // 0..199: 8 XCD groups x 25 blocks
    const int xcd = b2 & (NXCD - 1);
    const int off = (b2 >> 3) * 256 + threadIdx.x;
    if (off < NPX) {
        int d = xcd * NPX + off;
        csr_src[row_ptr[d]] = (u16)d;       // self-loop at slot 0
    }
}

// ---------------- fused GAT layer 1: 4 nodes/block (1/wave), register-only ----------------
__global__ void k_gat1(const int* __restrict__ row_ptr, const u16* __restrict__ csr_src,
                       const float* __restrict__ als, const float* __restrict__ ald,
                       const __half2* __restrict__ xw, __half2* __restrict__ out) {
    const int bi = blockIdx.x;
    const int s = bi & (NXCD - 1);                    // shard = presumed XCD
    const int off = (bi >> 3) * 4 + (threadIdx.x >> 6);
    if (off >= NPX) return;                            // no barriers in kernel: safe
    const int d = s * NPX + off;
    const int lane = threadIdx.x & 63;
    const int beg = row_ptr[d];
    const int deg = row_ptr[d + 1] - beg;
    const int h = lane >> 4;

    const float4 adv = *(const float4*)(ald + d * NH);

    float ax = 0.f, ay = 0.f, den = 0.f;
    for (int base = 0; base < deg; base += 64) {
        int cnt = min(64, deg - base);
        int sv = 0;
        float e0 = 0.f, e1 = 0.f, e2 = 0.f, e3 = 0.f;
        if (lane < cnt) {
            sv = csr_src[beg + base + lane];
            const float4 a = *(const float4*)(als + sv * NH);
            e0 = __expf(lrelu(a.x + adv.x, 0.2f));
            e1 = __expf(lrelu(a.y + adv.y, 0.2f));
            e2 = __expf(lrelu(a.z + adv.z, 0.2f));
            e3 = __expf(lrelu(a.w + adv.w, 0.2f));
        }
        for (int i = 0; i < cnt; i++) {               // i uniform -> readlane broadcasts
            float a0 = __shfl(e0, i), a1 = __shfl(e1, i);
            float a2 = __shfl(e2, i), a3 = __shfl(e3, i);
            int   si = __shfl(sv, i);
            float al = (h == 0) ? a0 : (h == 1) ? a1 : (h == 2) ? a2 : a3;
            float2 v = __half22float2(xw[(size_t)si * 64 + lane]);
            den += al; ax += al * v.x; ay += al * v.y;
        }
    }
    float inv = 1.f / (den + 1e-16f);
    __half2 hv;
    hv.x = __float2half(ax * inv);
    hv.y = __float2half(ay * inv);
    out[(size_t)d * 64 + lane] = hv;
}

// ---------------- BN1 stats from fp16 agg ----------------
__global__ void k_bnstats1h(const __half2* __restrict__ x, float* __restrict__ bp) {
    int t = threadIdx.x, bid = blockIdx.x;  // 64 threads
    float s0 = 0.f, q0 = 0.f, s1 = 0.f, q1 = 0.f;
    for (int r = bid; r < NN; r += NBP) {
        float2 f = __half22float2(x[(size_t)r * 64 + t]);
        s0 += f.x; q0 += f.x * f.x;
        s1 += f.y; q1 += f.y * f.y;
    }
    bp[bid * D1 + 2 * t] = s0;
    bp[bid * D1 + 2 * t + 1] = s1;
    bp[NBP * D1 + bid * D1 + 2 * t] = q0;
    bp[NBP * D1 + bid * D1 + 2 * t + 1] = q1;
}

template <int D>
__global__ void k_bnstats(const float* __restrict__ x, float* __restrict__ bp) {
    int j = threadIdx.x, bid = blockIdx.x;
    float s = 0.f, q = 0.f;
    for (int r = bid; r < NN; r += NBP) {
        float v = x[(size_t)r * D + j];
        s += v; q += v * v;
    }
    bp[bid * D + j] = s;
    bp[NBP * D + bid * D + j] = q;
}

template <int D>
__global__ void k_bnreduce(const float* __restrict__ bp, const float* __restrict__ g,
                           const float* __restrict__ b, float* __restrict__ scale,
                           float* __restrict__ shift) {
    __shared__ float rs[256], rq[256];
    int j = blockIdx.x, t = threadIdx.x;
    float s = 0.f, q = 0.f;
    for (int i = t; i < NBP; i += 256) {
        s += bp[i * D + j];
        q += bp[NBP * D + i * D + j];
    }
    rs[t] = s; rq[t] = q;
    __syncthreads();
    for (int st = 128; st >= 1; st >>= 1) {
        if (t < st) { rs[t] += rs[t + st]; rq[t] += rq[t + st]; }
        __syncthreads();
    }
    if (t == 0) {
        float mu = rs[0] / (float)NN;
        float var = rq[0] / (float)NN - mu * mu;
        float sc = rsqrtf(var + 1e-5f) * g[j];
        scale[j] = sc;
        shift[j] = b[j] - mu * sc;
    }
}

// final BN+lrelu for layer-2 output (float4)
__global__ void k_bnapply2(const float* __restrict__ x, const float* __restrict__ scale,
                           const float* __restrict__ shift, float* __restrict__ y) {
    int idx = blockIdx.x * blockDim.x + threadIdx.x;
    if (idx >= NN * D2 / 4) return;
    float4 v = ((const float4*)x)[idx];
    int c = (idx * 4) & (D2 - 1);
    v.x = lrelu(v.x * scale[c + 0] + shift[c + 0], 0.01f);
    v.y = lrelu(v.y * scale[c + 1] + shift[c + 1], 0.01f);
    v.z = lrelu(v.z * scale[c + 2] + shift[c + 2], 0.01f);
    v.w = lrelu(v.w * scale[c + 3] + shift[c + 3], 0.01f);
    ((float4*)y)[idx] = v;
}

// ---------------- GEMM2 via MFMA, fp16 A in, fused BN1-apply + lrelu ----------------
__global__ void k_gemm2m(const __half* __restrict__ x, const float* __restrict__ scale,
                         const float* __restrict__ shift, const half8_t* __restrict__ wp,
                         const float* __restrict__ as, const float* __restrict__ ad,
                         __half* __restrict__ xw, float* __restrict__ al_s, float* __restrict__ al_d) {
    const int l = threadIdx.x;
    const int row0 = blockIdx.x * 16;
    const int c = l & 15, g = l >> 4;
    const __half* xrow = x + (size_t)(row0 + c) * D1;

    f32x4_t acc[4];
#pragma unroll
    for (int nt = 0; nt < 4; nt++) acc[nt] = (f32x4_t){0.f, 0.f, 0.f, 0.f};

#pragma unroll
    for (int kk = 0; kk < 4; kk++) {
        const int koff = kk * 32 + g * 8;
        half8_t a8 = *(const half8_t*)(xrow + koff);
        f32x4_t sc0 = *(const f32x4_t*)(scale + koff);
        f32x4_t sc1 = *(const f32x4_t*)(scale + koff + 4);
        f32x4_t sh0 = *(const f32x4_t*)(shift + koff);
        f32x4_t sh1 = *(const f32x4_t*)(shift + koff + 4);
        half8_t af;
#pragma unroll
        for (int i = 0; i < 4; i++) {
            af[i]     = (_Float16)lrelu((float)a8[i] * sc0[i] + sh0[i], 0.01f);
            af[i + 4] = (_Float16)lrelu((float)a8[i + 4] * sc1[i] + sh1[i], 0.01f);
        }
#pragma unroll
        for (int nt = 0; nt < 4; nt++) {
            half8_t bf = wp[(kk * 4 + nt) * 64 + l];
            acc[nt] = __builtin_amdgcn_mfma_f32_16x16x32_f16(af, bf, acc[nt], 0, 0, 0);
        }
    }

    float asv[4], adv[4];
#pragma unroll
    for (int nt = 0; nt < 4; nt++) { asv[nt] = as[nt * 16 + c]; adv[nt] = ad[nt * 16 + c]; }

#pragma unroll
    for (int r = 0; r < 4; r++) {
        const int row = row0 + g * 4 + r;
        __half* xwr = xw + (size_t)row * D2;
        float hs = 0.f, hd = 0.f;
#pragma unroll
        for (int nt = 0; nt < 4; nt++) {
            float v = acc[nt][r];
            xwr[nt * 16 + c] = __float2half(v);
            hs += v * asv[nt];
            hd += v * adv[nt];
        }
#pragma unroll
        for (int m = 1; m <= 8; m <<= 1) { hs += __shfl_xor(hs, m); hd += __shfl_xor(hd, m); }
        if (c == 0) { al_s[row] = hs; al_d[row] = hd; }
    }
}

// ---------------- fused GAT layer 2: 4 nodes/block (1/wave), register-only ----------------
__global__ void k_gat2(const int* __restrict__ row_ptr, const u16* __restrict__ csr_src,
                       const float* __restrict__ als, const float* __restrict__ ald,
                       const __half2* __restrict__ xw, float* __restrict__ out) {
    const int bi = blockIdx.x;
    const int s = bi & (NXCD - 1);
    const int off = (bi >> 3) * 4 + (threadIdx.x >> 6);
    if (off >= NPX) return;
    const int d = s * NPX + off;
    const int lane = threadIdx.x & 63;
    const int beg = row_ptr[d];
    const int deg = row_ptr[d + 1] - beg;
    const int sub = lane >> 5, l = lane & 31;

    const float add = ald[d];
    float ax = 0.f, ay = 0.f, den = 0.f;
    for (int base = 0; base < deg; base += 64) {
        int cnt = min(64, deg - base);
        int sv = 0; float e = 0.f;
        if (lane < cnt) {
            sv = csr_src[beg + base + lane];
            e = __expf(lrelu(als[sv] + add, 0.2f));
        }
        int np = (cnt + 1) >> 1;
        for (int i = 0; i < np; i++) {
            int idx = 2 * i + sub;
            float al = __shfl(e, idx);
            int  si  = __shfl(sv, idx);
            float2 v = __half22float2(xw[(size_t)si * 32 + l]);
            den += al; ax += al * v.x; ay += al * v.y;
        }
    }
    ax += __shfl_xor(ax, 32); ay += __shfl_xor(ay, 32); den += __shfl_xor(den, 32);
    if (lane < 32) {
        float inv = 1.f / (den + 1e-16f);
        *(float2*)(out + (size_t)d * D2 + 2 * l) = make_float2(ax * inv, ay * inv);
    }
}

extern "C" void kernel_launch(void* const* d_in, const int* in_sizes, int n_in,
                              void* d_out, int out_size, void* d_ws, size_t ws_size,
                              hipStream_t stream) {
    const float* x   = (const float*)d_in[0];
    const int*   ei  = (const int*)d_in[2];
    const float* W1  = (const float*)d_in[3];
    const float* as1 = (const float*)d_in[4];
    const float* ad1 = (const float*)d_in[5];
    const float* g1  = (const float*)d_in[7];
    const float* be1 = (const float*)d_in[8];
    const float* W2  = (const float*)d_in[9];
    const float* as2 = (const float*)d_in[10];
    const float* ad2 = (const float*)d_in[11];
    const float* g2  = (const float*)d_in[13];
    const float* be2 = (const float*)d_in[14];
    float* out = (float*)d_out;

    float* ws = (float*)d_ws;
    // ---- layout (float offsets); footprint identical to R6-R13 (proven < ws_size) ----
    __half* xw1  = (__half*)ws;
    __half* xw2  = (__half*)ws;
    float* bp    = ws + 1600000;
    unsigned* ulist = (unsigned*)(ws + 3200000);   // 1024*1024 u32 -> [3.2M, 4,248,576)
    u16*   plist  = (u16*)(ws + 4248576);          // 1024*1024 u16 -> [4248576, 4772864)
    int*   mcount = (int*)(ws + 4772864);          // 1024 ints
    int*   cnt    = (int*)(ws + 4773888);          // 50,000 ints -> ends 4,823,888 < 6.4M
    float* al_s2 = ws + 3200000;         // 50k (CSR scratch dead by then)
    float* al_d2 = ws + 3250000;         // 50k
    float* al_s1 = ws + 6400000;         // 200k
    float* al_d1 = al_s1 + 200000;       // 200k
    float* aggF  = al_d1 + 200000;       // agg region base, 3.2M floats
    __half* agg1 = (__half*)aggF;        // 6.4M halves, live gat1..gemm2m
    u16*   partial = (u16*)aggF;         // 1024*6250 u16 = whole agg region (dead before gat1)
    int*   row_ptr = (int*)(aggF + 3200000);     // 50,001 ints
    int*   part    = row_ptr + 50001;            // 249 ints (pad for 16B-aligned st)
    float* st      = (float*)(part + 249);       // 384 floats
    u16*   csr_src = (u16*)(st + 768);           // 850,000 u16
    __half* Wp1    = (__half*)(csr_src + 850000);  // 16384 halves
    __half* Wp2    = Wp1 + 16384;                  // 8192 halves

    // ---- init + CSR build (LDS u16 hist, zero global atomics, no memsets) + GEMM1 ----
    k_prepw<<<96, 256, 0, stream>>>(W1, W2, Wp1, Wp2);
    k_histgemm1<<<NHB + (NN / 16 + 3) / 4, 256, 0, stream>>>(
        ei, ulist, plist, partial, mcount, x, (const half8_t*)Wp1, as1, ad1, xw1, al_s1, al_d1);
    k_prefsum<<<NB_SCAN, 256, 0, stream>>>(partial, cnt, part);
    k_scanfix<<<NB_SCAN, 256, 0, stream>>>(cnt, part, row_ptr);
    k_fill_x<<<NHB + 200, 256, 0, stream>>>(row_ptr, partial, ulist, plist, mcount, csr_src);

    // ---- layer 1 ----
    k_gat1<<<NGB, 256, 0, stream>>>(row_ptr, csr_src, al_s1, al_d1, (const __half2*)xw1,
                                    (__half2*)agg1);
    k_bnstats1h<<<NBP, 64, 0, stream>>>((const __half2*)agg1, bp);
    k_bnreduce<D1><<<D1, 256, 0, stream>>>(bp, g1, be1, st, st + 128);

    // ---- layer 2 (BN1 apply fused into gemm2's A-read) ----
    k_gemm2m<<<NN / 16, 64, 0, stream>>>(agg1, st, st + 128, (const half8_t*)Wp2, as2, ad2,
                                         xw2, al_s2, al_d2);
    k_gat2<<<NGB, 256, 0, stream>>>(row_ptr, csr_src, al_s2, al_d2, (const __half2*)xw2, out);
    k_bnstats<D2><<<NBP, D2, 0, stream>>>(out, bp);
    k_bnreduce<D2><<<D2, 256, 0, stream>>>(bp, g2, be2, st + 256, st + 320);
    k_bnapply2<<<(NN * D2 / 4 + 255) / 256, 256, 0, stream>>>(out, st + 256, st + 320, out);
}

// Round 15
// 180.416 us; speedup vs baseline: 1.1816x; 1.1816x over previous
//
#include <hip/hip_runtime.h>
#include <hip/hip_fp16.h>

#define NN 50000        // nodes
#define NE 800000       // edges (without self loops; 800000 = 128*6250)
#define ET 850000       // edges + self loops
#define GD 128          // input feature dim
#define D1 128          // HEADS*H1
#define NH 4            // heads layer 1
#define D2 64           // layer-2 dim
#define NB_SCAN 196     // ceil(NN/256)
#define NBP 1024        // bn partial blocks
#define NXCD 8
#define NPX 6250        // nodes per shard (= per XCD for gat swizzle)
#define HSL 128         // hist slices
#define ESL 6250        // edges per slice = NE/HSL (exact)
#define NHB 1024        // hist blocks = NXCD * HSL
#define CAP 1024        // compact-list capacity per block (mean 781, ~9 sigma margin)

typedef unsigned short u16;
typedef _Float16 half8_t __attribute__((ext_vector_type(8)));
typedef float    f32x4_t __attribute__((ext_vector_type(4)));

__device__ __forceinline__ float lrelu(float x, float s) { return x > 0.f ? x : s * x; }

// ---------------- init: permute/cvt weights ----------------
__global__ void k_prepw(const float* __restrict__ W1, const float* __restrict__ W2,
                        __half* __restrict__ Wp1, __half* __restrict__ Wp2) {
    int idx = blockIdx.x * 256 + threadIdx.x;
    if (idx < 16384) {
        int i = idx & 7, l = (idx >> 3) & 63, nt = (idx >> 9) & 7, kk = idx >> 12;
        int k = kk * 32 + (l >> 4) * 8 + i, n = nt * 16 + (l & 15);
        Wp1[idx] = __float2half(W1[k * D1 + n]);
    } else if (idx < 24576) {
        int x2 = idx - 16384;
        int i = x2 & 7, l = (x2 >> 3) & 63, nt = (x2 >> 9) & 3, kk = x2 >> 11;
        int k = kk * 32 + (l >> 4) * 8 + i, n = nt * 16 + (l & 15);
        Wp2[x2] = __float2half(W2[k * D2 + n]);
    }
}

// ---------------- fused: LDS u16-hist CSR build (blocks [0,NHB)) + MFMA GEMM1 ----------------
__global__ void k_histgemm1(const int* __restrict__ ei,
                            unsigned* __restrict__ ulist, u16* __restrict__ plist,
                            u16* __restrict__ partial, int* __restrict__ mcount,
                            const float* __restrict__ x, const half8_t* __restrict__ wp,
                            const float* __restrict__ as, const float* __restrict__ ad,
                            __half* __restrict__ xw, float* __restrict__ al_s,
                            float* __restrict__ al_d) {
    __shared__ unsigned lh[NPX / 2];   // 3125 u32 = 6250 u16 counters
    __shared__ unsigned lk;
    if (blockIdx.x < NHB) {
        const int s = blockIdx.x & (NXCD - 1), j = blockIdx.x >> 3;
        const int lo = s * NPX;
        for (int i = threadIdx.x; i < NPX / 2; i += 256) lh[i] = 0u;
        if (threadIdx.x == 0) lk = 0u;
        __syncthreads();
        const int e0 = j * ESL;
        const size_t ub = (size_t)blockIdx.x * CAP;
        for (int e = e0 + threadIdx.x; e < e0 + ESL; e += 256) {
            int d = ei[NE + e];
            unsigned dl = (unsigned)(d - lo);
            if (dl < (unsigned)NPX) {
                unsigned old = atomicAdd(&lh[dl >> 1], (dl & 1) ? 0x10000u : 1u);
                unsigned p = (old >> ((dl & 1) * 16)) & 0xffffu;
                unsigned k = atomicAdd(&lk, 1u);
                if (k < CAP) {
                    ulist[ub + k] = (dl << 16) | (unsigned)ei[e];
                    plist[ub + k] = (u16)p;
                }
            }
        }
        __syncthreads();
        unsigned* pout = (unsigned*)(partial + (size_t)blockIdx.x * NPX);
        for (int i = threadIdx.x; i < NPX / 2; i += 256) pout[i] = lh[i];
        if (threadIdx.x == 0) mcount[blockIdx.x] = (int)lk;
        return;
    }
    const int strip = (blockIdx.x - NHB) * 4 + (threadIdx.x >> 6);
    if (strip >= NN / 16) return;
    const int l = threadIdx.x & 63;
    const int row0 = strip * 16;
    const int c = l & 15, g = l >> 4;
    const float* xrow = x + (size_t)(row0 + c) * GD;

    f32x4_t acc[8];
#pragma unroll
    for (int nt = 0; nt < 8; nt++) acc[nt] = (f32x4_t){0.f, 0.f, 0.f, 0.f};

#pragma unroll
    for (int kk = 0; kk < 4; kk++) {
        const int koff = kk * 32 + g * 8;
        f32x4_t a0 = *(const f32x4_t*)(xrow + koff);
        f32x4_t a1 = *(const f32x4_t*)(xrow + koff + 4);
        half8_t af;
#pragma unroll
        for (int i = 0; i < 4; i++) { af[i] = (_Float16)a0[i]; af[i + 4] = (_Float16)a1[i]; }
#pragma unroll
        for (int nt = 0; nt < 8; nt++) {
            half8_t bf = wp[(kk * 8 + nt) * 64 + l];
            acc[nt] = __builtin_amdgcn_mfma_f32_16x16x32_f16(af, bf, acc[nt], 0, 0, 0);
        }
    }

    float asv[8], adv[8];
#pragma unroll
    for (int nt = 0; nt < 8; nt++) { asv[nt] = as[nt * 16 + c]; adv[nt] = ad[nt * 16 + c]; }

#pragma unroll
    for (int r = 0; r < 4; r++) {
        const int row = row0 + g * 4 + r;
        __half* xwr = xw + (size_t)row * D1;
        float hs[4] = {0.f, 0.f, 0.f, 0.f}, hd[4] = {0.f, 0.f, 0.f, 0.f};
#pragma unroll
        for (int nt = 0; nt < 8; nt++) {
            float v = acc[nt][r];
            xwr[nt * 16 + c] = __float2half(v);
            hs[nt >> 1] += v * asv[nt];
            hd[nt >> 1] += v * adv[nt];
        }
#pragma unroll
        for (int m = 1; m <= 8; m <<= 1) {
#pragma unroll
            for (int h = 0; h < 4; h++) { hs[h] += __shfl_xor(hs[h], m); hd[h] += __shfl_xor(hd[h], m); }
        }
        if (c == 0) {
#pragma unroll
            for (int h = 0; h < 4; h++) { al_s[row * NH + h] = hs[h]; al_d[row * NH + h] = hd[h]; }
        }
    }
}

// ---------------- merged: per-node slice-prefix (in place) + cnt + block sums ----------------
__global__ void k_prefsum(u16* __restrict__ partial, int* __restrict__ cnt,
                          int* __restrict__ part) {
    __shared__ int r[256];
    int t = threadIdx.x, d = blockIdx.x * 256 + t;
    int run = 0;
    if (d < NN) {
        int s = d / NPX, dl = d - s * NPX;
        for (int j = 0; j < HSL; j++) {
            size_t idx = (size_t)(j * NXCD + s) * NPX + dl;   // block b = j*8+s
            int v = partial[idx];
            partial[idx] = (u16)run;
            run += v;
        }
        run += 1;             // +1: self-loop occupies slot 0 of each row
        cnt[d] = run;
    }
    r[t] = (d < NN) ? run : 0;
    __syncthreads();
    for (int s2 = 128; s2 >= 1; s2 >>= 1) {
        if (t < s2) r[t] += r[t + s2];
        __syncthreads();
    }
    if (t == 0) part[blockIdx.x] = r[0];
}

__global__ void k_scanfix(const int* __restrict__ cnt, const int* __restrict__ part,
                          int* __restrict__ row_ptr) {
    __shared__ int pp[256];
    __shared__ int r[256];
    int b = blockIdx.x, t = threadIdx.x, i = b * 256 + t;
    pp[t] = (t < NB_SCAN) ? part[t] : 0;
    int v = (i < NN) ? cnt[i] : 0;
    r[t] = v;
    __syncthreads();
    for (int off = 1; off < 256; off <<= 1) {
        int pv = (t >= off) ? pp[t - off] : 0;
        int rv = (t >= off) ? r[t - off] : 0;
        __syncthreads();
        pp[t] += pv; r[t] += rv;
        __syncthreads();
    }
    int pbase = b ? pp[b - 1] : 0;
    if (i < NN) row_ptr[i] = pbase + (t ? r[t - 1] : 0);
    if (i == NN - 1) row_ptr[NN] = pbase + r[t];
}

// ---------------- CSR fill from compact lists + self-loops (no atomics) ----------------
__global__ void k_fill_x(const int* __restrict__ row_ptr, const u16* __restrict__ P,
                         const unsigned* __restrict__ ulist, const u16* __restrict__ plist,
                         const int* __restrict__ mcount, u16* __restrict__ csr_src) {
    const int b = blockIdx.x;
    if (b < NHB) {
        const int s = b & (NXCD - 1);
        const int lo = s * NPX;
        const int m = min(mcount[b], CAP);
        const size_t ub = (size_t)b * CAP;
        const u16* Pb = P + (size_t)b * NPX;
        for (int k = threadIdx.x; k < m; k += 256) {
            unsigned u = ulist[ub + k];
            int dl = (int)(u >> 16);
            int base = row_ptr[lo + dl] + 1 + (int)Pb[dl] + (int)plist[ub + k];
            csr_src[base] = (u16)(u & 0xffffu);
        }
        return;
    }
    const int b2 = b - NHB;                 // 0..199: 8 XCD groups x 25 blocks
    const int xcd = b2 & (NXCD - 1);
    const int off = (b2 >> 3) * 256 + threadIdx.x;
    if (off < NPX) {
        int d = xcd * NPX + off;
        csr_src[row_ptr[d]] = (u16)d;       // self-loop at slot 0
    }
}

// ---------------- fused GAT layer 1: one wave per destination (LDS broadcast) ----------------
__global__ void k_gat1(const int* __restrict__ row_ptr, const u16* __restrict__ csr_src,
                       const float* __restrict__ als, const float* __restrict__ ald,
                       const __half2* __restrict__ xw, __half2* __restrict__ out) {
    const int b = blockIdx.x;
    const int d = (b & (NXCD - 1)) * NPX + (b >> 3);
    const int beg = row_ptr[d];
    const int deg = row_ptr[d + 1] - beg;
    const int lane = threadIdx.x;  // 64

    __shared__ int   s_src[64];
    __shared__ float s_al[64 * NH];

    const float4 adv = *(const float4*)(ald + d * NH);
    const int h = lane >> 4;

    float ax = 0.f, ay = 0.f, den = 0.f;
    for (int base = 0; base < deg; base += 64) {
        int cnt = min(64, deg - base);
        if (lane < cnt) {
            int s = csr_src[beg + base + lane];
            s_src[lane] = s;
            const float4 a = *(const float4*)(als + s * NH);
            s_al[lane * NH + 0] = __expf(lrelu(a.x + adv.x, 0.2f));
            s_al[lane * NH + 1] = __expf(lrelu(a.y + adv.y, 0.2f));
            s_al[lane * NH + 2] = __expf(lrelu(a.z + adv.z, 0.2f));
            s_al[lane * NH + 3] = __expf(lrelu(a.w + adv.w, 0.2f));
        }
        __syncthreads();
#pragma unroll 4
        for (int i = 0; i < cnt; i++) {
            float al = s_al[i * NH + h];
            float2 v = __half22float2(xw[(size_t)s_src[i] * 64 + lane]);
            den += al; ax += al * v.x; ay += al * v.y;
        }
        __syncthreads();
    }
    float inv = 1.f / (den + 1e-16f);
    __half2 hv;
    hv.x = __float2half(ax * inv);
    hv.y = __float2half(ay * inv);
    out[(size_t)d * 64 + lane] = hv;
}

// ---------------- BN1 stats from fp16 agg ----------------
__global__ void k_bnstats1h(const __half2* __restrict__ x, float* __restrict__ bp) {
    int t = threadIdx.x, bid = blockIdx.x;  // 64 threads
    float s0 = 0.f, q0 = 0.f, s1 = 0.f, q1 = 0.f;
    for (int r = bid; r < NN; r += NBP) {
        float2 f = __half22float2(x[(size_t)r * 64 + t]);
        s0 += f.x; q0 += f.x * f.x;
        s1 += f.y; q1 += f.y * f.y;
    }
    bp[bid * D1 + 2 * t] = s0;
    bp[bid * D1 + 2 * t + 1] = s1;
    bp[NBP * D1 + bid * D1 + 2 * t] = q0;
    bp[NBP * D1 + bid * D1 + 2 * t + 1] = q1;
}

template <int D>
__global__ void k_bnstats(const float* __restrict__ x, float* __restrict__ bp) {
    int j = threadIdx.x, bid = blockIdx.x;
    float s = 0.f, q = 0.f;
    for (int r = bid; r < NN; r += NBP) {
        float v = x[(size_t)r * D + j];
        s += v; q += v * v;
    }
    bp[bid * D + j] = s;
    bp[NBP * D + bid * D + j] = q;
}

template <int D>
__global__ void k_bnreduce(const float* __restrict__ bp, const float* __restrict__ g,
                           const float* __restrict__ b, float* __restrict__ scale,
                           float* __restrict__ shift) {
    __shared__ float rs[256], rq[256];
    int j = blockIdx.x, t = threadIdx.x;
    float s = 0.f, q = 0.f;
    for (int i = t; i < NBP; i += 256) {
        s += bp[i * D + j];
        q += bp[NBP * D + i * D + j];
    }
    rs[t] = s; rq[t] = q;
    __syncthreads();
    for (int st = 128; st >= 1; st >>= 1) {
        if (t < st) { rs[t] += rs[t + st]; rq[t] += rq[t + st]; }
        __syncthreads();
    }
    if (t == 0) {
        float mu = rs[0] / (float)NN;
        float var = rq[0] / (float)NN - mu * mu;
        float sc = rsqrtf(var + 1e-5f) * g[j];
        scale[j] = sc;
        shift[j] = b[j] - mu * sc;
    }
}

// final BN+lrelu for layer-2 output (float4)
__global__ void k_bnapply2(const float* __restrict__ x, const float* __restrict__ scale,
                           const float* __restrict__ shift, float* __restrict__ y) {
    int idx = blockIdx.x * blockDim.x + threadIdx.x;
    if (idx >= NN * D2 / 4) return;
    float4 v = ((const float4*)x)[idx];
    int c = (idx * 4) & (D2 - 1);
    v.x = lrelu(v.x * scale[c + 0] + shift[c + 0], 0.01f);
    v.y = lrelu(v.y * scale[c + 1] + shift[c + 1], 0.01f);
    v.z = lrelu(v.z * scale[c + 2] + shift[c + 2], 0.01f);
    v.w = lrelu(v.w * scale[c + 3] + shift[c + 3], 0.01f);
    ((float4*)y)[idx] = v;
}

// ---------------- GEMM2 via MFMA, fp16 A in, fused BN1-apply + lrelu ----------------
__global__ void k_gemm2m(const __half* __restrict__ x, const float* __restrict__ scale,
                         const float* __restrict__ shift, const half8_t* __restrict__ wp,
                         const float* __restrict__ as, const float* __restrict__ ad,
                         __half* __restrict__ xw, float* __restrict__ al_s, float* __restrict__ al_d) {
    const int l = threadIdx.x;
    const int row0 = blockIdx.x * 16;
    const int c = l & 15, g = l >> 4;
    const __half* xrow = x + (size_t)(row0 + c) * D1;

    f32x4_t acc[4];
#pragma unroll
    for (int nt = 0; nt < 4; nt++) acc[nt] = (f32x4_t){0.f, 0.f, 0.f, 0.f};

#pragma unroll
    for (int kk = 0; kk < 4; kk++) {
        const int koff = kk * 32 + g * 8;
        half8_t a8 = *(const half8_t*)(xrow + koff);
        f32x4_t sc0 = *(const f32x4_t*)(scale + koff);
        f32x4_t sc1 = *(const f32x4_t*)(scale + koff + 4);
        f32x4_t sh0 = *(const f32x4_t*)(shift + koff);
        f32x4_t sh1 = *(const f32x4_t*)(shift + koff + 4);
        half8_t af;
#pragma unroll
        for (int i = 0; i < 4; i++) {
            af[i]     = (_Float16)lrelu((float)a8[i] * sc0[i] + sh0[i], 0.01f);
            af[i + 4] = (_Float16)lrelu((float)a8[i + 4] * sc1[i] + sh1[i], 0.01f);
        }
#pragma unroll
        for (int nt = 0; nt < 4; nt++) {
            half8_t bf = wp[(kk * 4 + nt) * 64 + l];
            acc[nt] = __builtin_amdgcn_mfma_f32_16x16x32_f16(af, bf, acc[nt], 0, 0, 0);
        }
    }

    float asv[4], adv[4];
#pragma unroll
    for (int nt = 0; nt < 4; nt++) { asv[nt] = as[nt * 16 + c]; adv[nt] = ad[nt * 16 + c]; }

#pragma unroll
    for (int r = 0; r < 4; r++) {
        const int row = row0 + g * 4 + r;
        __half* xwr = xw + (size_t)row * D2;
        float hs = 0.f, hd = 0.f;
#pragma unroll
        for (int nt = 0; nt < 4; nt++) {
            float v = acc[nt][r];
            xwr[nt * 16 + c] = __float2half(v);
            hs += v * asv[nt];
            hd += v * adv[nt];
        }
#pragma unroll
        for (int m = 1; m <= 8; m <<= 1) { hs += __shfl_xor(hs, m); hd += __shfl_xor(hd, m); }
        if (c == 0) { al_s[row] = hs; al_d[row] = hd; }
    }
}

// ---------------- fused GAT layer 2: one wave per destination, register-only ----------------
__global__ void k_gat2(const int* __restrict__ row_ptr, const u16* __restrict__ csr_src,
                       const float* __restrict__ als, const float* __restrict__ ald,
                       const __half2* __restrict__ xw, float* __restrict__ out) {
    const int b = blockIdx.x;
    const int d = (b & (NXCD - 1)) * NPX + (b >> 3);
    const int beg = row_ptr[d];
    const int deg = row_ptr[d + 1] - beg;
    const int lane = threadIdx.x;
    const int sub = lane >> 5, l = lane & 31;

    const float add = ald[d];
    float ax = 0.f, ay = 0.f, den = 0.f;
    for (int base = 0; base < deg; base += 64) {
        int cnt = min(64, deg - base);
        int sv = 0; float e = 0.f;
        if (lane < cnt) {
            sv = csr_src[beg + base + lane];
            e = __expf(lrelu(als[sv] + add, 0.2f));
        }
        int np = (cnt + 1) >> 1;
        for (int i = 0; i < np; i++) {
            int idx = 2 * i + sub;
            float al = __shfl(e, idx);
            int  si  = __shfl(sv, idx);
            float2 v = __half22float2(xw[(size_t)si * 32 + l]);
            den += al; ax += al * v.x; ay += al * v.y;
        }
    }
    ax += __shfl_xor(ax, 32); ay += __shfl_xor(ay, 32); den += __shfl_xor(den, 32);
    if (lane < 32) {
        float inv = 1.f / (den + 1e-16f);
        *(float2*)(out + (size_t)d * D2 + 2 * l) = make_float2(ax * inv, ay * inv);
    }
}

extern "C" void kernel_launch(void* const* d_in, const int* in_sizes, int n_in,
                              void* d_out, int out_size, void* d_ws, size_t ws_size,
                              hipStream_t stream) {
    const float* x   = (const float*)d_in[0];
    const int*   ei  = (const int*)d_in[2];
    const float* W1  = (const float*)d_in[3];
    const float* as1 = (const float*)d_in[4];
    const float* ad1 = (const float*)d_in[5];
    const float* g1  = (const float*)d_in[7];
    const float* be1 = (const float*)d_in[8];
    const float* W2  = (const float*)d_in[9];
    const float* as2 = (const float*)d_in[10];
    const float* ad2 = (const float*)d_in[11];
    const float* g2  = (const float*)d_in[13];
    const float* be2 = (const float*)d_in[14];
    float* out = (float*)d_out;

    float* ws = (float*)d_ws;
    // ---- layout (float offsets); footprint identical to R6-R14 (proven < ws_size) ----
    __half* xw1  = (__half*)ws;
    __half* xw2  = (__half*)ws;
    float* bp    = ws + 1600000;
    unsigned* ulist = (unsigned*)(ws + 3200000);   // 1024*1024 u32 -> [3.2M, 4,248,576)
    u16*   plist  = (u16*)(ws + 4248576);          // 1024*1024 u16 -> [4248576, 4772864)
    int*   mcount = (int*)(ws + 4772864);          // 1024 ints
    int*   cnt    = (int*)(ws + 4773888);          // 50,000 ints -> ends 4,823,888 < 6.4M
    float* al_s2 = ws + 3200000;         // 50k (CSR scratch dead by then)
    float* al_d2 = ws + 3250000;         // 50k
    float* al_s1 = ws + 6400000;         // 200k
    float* al_d1 = al_s1 + 200000;       // 200k
    float* aggF  = al_d1 + 200000;       // agg region base, 3.2M floats
    __half* agg1 = (__half*)aggF;        // 6.4M halves, live gat1..gemm2m
    u16*   partial = (u16*)aggF;         // 1024*6250 u16 = whole agg region (dead before gat1)
    int*   row_ptr = (int*)(aggF + 3200000);     // 50,001 ints
    int*   part    = row_ptr + 50001;            // 249 ints (pad for 16B-aligned st)
    float* st      = (float*)(part + 249);       // 384 floats
    u16*   csr_src = (u16*)(st + 768);           // 850,000 u16
    __half* Wp1    = (__half*)(csr_src + 850000);  // 16384 halves
    __half* Wp2    = Wp1 + 16384;                  // 8192 halves

    // ---- init + CSR build (LDS u16 hist, zero global atomics, no memsets) + GEMM1 ----
    k_prepw<<<96, 256, 0, stream>>>(W1, W2, Wp1, Wp2);
    k_histgemm1<<<NHB + (NN / 16 + 3) / 4, 256, 0, stream>>>(
        ei, ulist, plist, partial, mcount, x, (const half8_t*)Wp1, as1, ad1, xw1, al_s1, al_d1);
    k_prefsum<<<NB_SCAN, 256, 0, stream>>>(partial, cnt, part);
    k_scanfix<<<NB_SCAN, 256, 0, stream>>>(cnt, part, row_ptr);
    k_fill_x<<<NHB + 200, 256, 0, stream>>>(row_ptr, partial, ulist, plist, mcount, csr_src);

    // ---- layer 1 ----
    k_gat1<<<NN, 64, 0, stream>>>(row_ptr, csr_src, al_s1, al_d1, (const __half2*)xw1,
                                  (__half2*)agg1);
    k_bnstats1h<<<NBP, 64, 0, stream>>>((const __half2*)agg1, bp);
    k_bnreduce<D1><<<D1, 256, 0, stream>>>(bp, g1, be1, st, st + 128);

    // ---- layer 2 (BN1 apply fused into gemm2's A-read) ----
    k_gemm2m<<<NN / 16, 64, 0, stream>>>(agg1, st, st + 128, (const half8_t*)Wp2, as2, ad2,
                                         xw2, al_s2, al_d2);
    k_gat2<<<NN, 64, 0, stream>>>(row_ptr, csr_src, al_s2, al_d2, (const __half2*)xw2, out);
    k_bnstats<D2><<<NBP, D2, 0, stream>>>(out, bp);
    k_bnreduce<D2><<<D2, 256, 0, stream>>>(bp, g2, be2, st + 256, st + 320);
    k_bnapply2<<<(NN * D2 / 4 + 255) / 256, 256, 0, stream>>>(out, st + 256, st + 320, out);
}